// Round 6
// baseline (74901.947 us; speedup 1.0000x reference)
//
#include <hip/hip_runtime.h>
#include <math.h>

#define NB 512      // batch
#define NT 512      // time
#define NCTRL 256
#define NWORD 128
#define NMEM 128
#define NDIN 64
#define NACT 448    // x(64) | read(128) | ctrl(256)
#define EPSF 1e-6f

// fp32 workspace layout (element offsets) — unchanged from round 4
#define OFF_WA   0        // [448][512]  fused r,z weights (transposed)
#define OFF_WNI  229376   // [192][256]  W_ih rows 512..767 transposed (inn)
#define OFF_WNH  278528   // [256][256]  W_hh rows 512..767 transposed (hn)
#define OFF_WH   344064   // [256][512]  heads: key|erase|add|beta|pad (transposed)
#define OFF_BA   475136   // [512]  b_ih[j]+b_hh[j]
#define OFF_BNI  475648   // [256]  b_ih[512+i]
#define OFF_BNH  475904   // [256]  b_hh[512+i]
#define OFF_BH   476160   // [512]  [b_key|b_erase|b_add|b_beta|0]
#define WS_FLOATS 476672

__device__ __forceinline__ float sigf(float x) { return 1.0f / (1.0f + expf(-x)); }
__device__ __forceinline__ float softplusf(float x) {
    return (x > 15.0f) ? x : log1pf(expf(x));
}

__global__ __launch_bounds__(256) void prep_kernel(
    const float* __restrict__ Wih, const float* __restrict__ bih,
    const float* __restrict__ Whh, const float* __restrict__ bhh,
    const float* __restrict__ Wkey, const float* __restrict__ bkey,
    const float* __restrict__ Wbeta, const float* __restrict__ bbeta,
    const float* __restrict__ Wer, const float* __restrict__ ber,
    const float* __restrict__ Wadd, const float* __restrict__ badd,
    float* __restrict__ ws)
{
    int i = blockIdx.x * 256 + threadIdx.x;
    if (i >= WS_FLOATS) return;
    float v;
    if (i < OFF_WNI) {                       // WA_T [448][512]
        int k = i >> 9, j = i & 511;
        v = (k < 192) ? Wih[j * 192 + k] : Whh[j * 256 + (k - 192)];
    } else if (i < OFF_WNH) {                // WNI_T [192][256]
        int i2 = i - OFF_WNI; int k = i2 >> 8, c = i2 & 255;
        v = Wih[(512 + c) * 192 + k];
    } else if (i < OFF_WH) {                 // WNH_T [256][256]
        int i2 = i - OFF_WNH; int k = i2 >> 8, c = i2 & 255;
        v = Whh[(512 + c) * 256 + k];
    } else if (i < OFF_BA) {                 // WH_T [256][512]
        int i2 = i - OFF_WH; int k = i2 >> 9, c = i2 & 511;
        if (c < 128)       v = Wkey[c * 256 + k];
        else if (c < 256)  v = Wer[(c - 128) * 256 + k];
        else if (c < 384)  v = Wadd[(c - 256) * 256 + k];
        else if (c == 384) v = Wbeta[k];
        else               v = 0.0f;
    } else if (i < OFF_BNI) {
        int j = i - OFF_BA;
        v = bih[j] + bhh[j];
    } else if (i < OFF_BNH) {
        v = bih[512 + (i - OFF_BNI)];
    } else if (i < OFF_BH) {
        v = bhh[512 + (i - OFF_BNH)];
    } else {
        int c = i - OFF_BH;
        if (c < 128)       v = bkey[c];
        else if (c < 256)  v = ber[c - 128];
        else if (c < 384)  v = badd[c - 256];
        else if (c == 384) v = bbeta[0];
        else               v = 0.0f;
    }
    ws[i] = v;
}

// Group-parallel memory module: lt in [0,256) within the group; all 512
// threads execute the same static barrier sequence. State writes (readv, M)
// guarded by `active` for packed-freeze semantics; scratch writes unguarded.
__device__ __forceinline__ void memory_step2(
    int lt, bool active, float (*M)[NWORD + 1],
    const float* keyv, const float* ev, const float* av,
    float* cosb, float* wb, float* part, float* readv, float* scal)
{
    if (lt < 64) {                        // ||k||
        float s = keyv[lt] * keyv[lt] + keyv[lt + 64] * keyv[lt + 64];
        #pragma unroll
        for (int o = 32; o >= 1; o >>= 1) s += __shfl_xor(s, o);
        if (lt == 0) scal[0] = 1.0f / (sqrtf(s) + EPSF);
    }
    __syncthreads();
    {                                      // cosine sim: 2 threads / mem row
        int rr = lt >> 1, hh = lt & 1;
        const float* Mr = &M[rr][hh * 64];
        const float* kk = keyv + hh * 64;
        float s2 = 0.f, sc = 0.f;
        #pragma unroll 8
        for (int j = 0; j < 64; ++j) { float m = Mr[j]; s2 = fmaf(m, m, s2); sc = fmaf(m, kk[j], sc); }
        s2 += __shfl_xor(s2, 1);
        sc += __shfl_xor(sc, 1);
        if (hh == 0) cosb[rr] = sc * scal[0] / (sqrtf(s2) + EPSF);
    }
    __syncthreads();
    if (lt < 64) {                        // softmax over 128 logits
        float beta = scal[1];
        float l0 = beta * cosb[lt], l1 = beta * cosb[lt + 64];
        float mx = fmaxf(l0, l1);
        #pragma unroll
        for (int o = 32; o >= 1; o >>= 1) mx = fmaxf(mx, __shfl_xor(mx, o));
        float e0 = expf(l0 - mx), e1 = expf(l1 - mx);
        float s = e0 + e1;
        #pragma unroll
        for (int o = 32; o >= 1; o >>= 1) s += __shfl_xor(s, o);
        float inv = 1.0f / s;
        wb[lt] = e0 * inv;
        wb[lt + 64] = e1 * inv;
    }
    __syncthreads();
    {                                      // read = w . OLD M (col-wise)
        int j = lt & 127, hf = lt >> 7;
        float p = 0.f;
        #pragma unroll 8
        for (int r = 0; r < 64; ++r) p = fmaf(wb[hf * 64 + r], M[hf * 64 + r][j], p);
        part[hf * 128 + j] = p;
    }
    __syncthreads();
    if (lt < 128 && active) readv[lt] = part[lt] + part[128 + lt];
    if (active) {                          // M = M - w*(e*M - a)
        int rr = lt >> 1, hh = lt & 1;
        float wr = wb[rr];
        #pragma unroll 8
        for (int i = 0; i < 64; ++i) {
            int j = hh * 64 + i;
            float m = M[rr][j];
            M[rr][j] = fmaf(-wr, fmaf(ev[j], m, -av[j]), m);
        }
    }
    __syncthreads();
}

// G=2 rows / 512-thread WG (8 waves = 2/SIMD). Both rows' M in LDS. Each
// weight dword loaded once, applied to both rows -> per-CU L2 traffic halves
// vs round 4. 256 WGs = 1/CU.
__global__ __launch_bounds__(512, 2) void ntm2(
    const float* __restrict__ data, const int* __restrict__ batch_sizes,
    const int* __restrict__ unsort, const float* __restrict__ M0,
    const float* __restrict__ ws, float* __restrict__ out)
{
    __shared__ float M[2][NMEM][NWORD + 1];          // 132 KB
    __shared__ float act[2][NACT];
    __shared__ float gpre[2][512], ginn[2][256], ghn[2][256];
    __shared__ float keyv[2][NWORD], ev_s[2][NWORD], av_s[2][NWORD], readv[2][NWORD];
    __shared__ float cosb[2][NMEM], wb[2][NMEM], part[2][2 * NWORD], scal[2][2];
    __shared__ int len_sh[2], slot_sh[2];

    const int tid = threadIdx.x;
    const int grp = tid >> 8, lt = tid & 255;
    const int b0 = blockIdx.x * 2;

    if (tid < 2) len_sh[tid] = 0;
    __syncthreads();
    {
        int bs = batch_sizes[tid];                   // NT == 512 == blockDim
        int u = unsort[tid];
        #pragma unroll
        for (int g = 0; g < 2; ++g) {
            if (bs > b0 + g) atomicAdd(&len_sh[g], 1);
            if (u == b0 + g) slot_sh[g] = tid;       // inverse permutation
        }
    }
    for (int i = tid; i < NMEM * NWORD; i += 512) {
        float v = M0[i];
        M[0][i >> 7][i & 127] = v;
        M[1][i >> 7][i & 127] = v;
    }
    if (lt < 128) readv[grp][lt] = 0.0f;
    act[grp][192 + lt] = 0.0f;                       // ctrl = 0
    __syncthreads();
    const int len0 = len_sh[0], len1 = len_sh[1];    // len0 >= len1 (packed)
    const int mylen = grp ? len1 : len0;
    const int lenmax = len0;

    const float bA = ws[OFF_BA + tid];
    const float bN = (tid < 256) ? ws[OFF_BNI + tid] : ws[OFF_BNH + tid - 256];
    const float bH = ws[OFF_BH + tid];

    for (int t = 0; t < lenmax; ++t) {
        // ---- stage x and read (ctrl region persists)
        if (lt < 64)  act[grp][lt] = data[((long)t * NB + b0 + grp) * NDIN + lt];
        if (lt < 128) act[grp][64 + lt] = readv[grp][lt];
        __syncthreads();

        // ---- fused r,z: thread -> col tid (512 cols), both rows
        float a0 = bA, a1 = bA;
        {
            const float* wa = ws + OFF_WA + tid;
            for (int k = 0; k < NACT; k += 4) {
                float4 x0 = *(const float4*)&act[0][k];
                float4 x1 = *(const float4*)&act[1][k];
                float w;
                w = wa[(k + 0) * 512]; a0 = fmaf(x0.x, w, a0); a1 = fmaf(x1.x, w, a1);
                w = wa[(k + 1) * 512]; a0 = fmaf(x0.y, w, a0); a1 = fmaf(x1.y, w, a1);
                w = wa[(k + 2) * 512]; a0 = fmaf(x0.z, w, a0); a1 = fmaf(x1.z, w, a1);
                w = wa[(k + 3) * 512]; a0 = fmaf(x0.w, w, a0); a1 = fmaf(x1.w, w, a1);
            }
        }
        gpre[0][tid] = a0; gpre[1][tid] = a1;
        // ---- n-gate: threads<256 -> inn col tid; threads>=256 -> hn col tid-256
        float n0 = bN, n1 = bN;
        if (tid < 256) {
            const float* wi = ws + OFF_WNI + tid;
            for (int k = 0; k < 192; k += 4) {
                float4 x0 = *(const float4*)&act[0][k];
                float4 x1 = *(const float4*)&act[1][k];
                float w;
                w = wi[(k + 0) * 256]; n0 = fmaf(x0.x, w, n0); n1 = fmaf(x1.x, w, n1);
                w = wi[(k + 1) * 256]; n0 = fmaf(x0.y, w, n0); n1 = fmaf(x1.y, w, n1);
                w = wi[(k + 2) * 256]; n0 = fmaf(x0.z, w, n0); n1 = fmaf(x1.z, w, n1);
                w = wi[(k + 3) * 256]; n0 = fmaf(x0.w, w, n0); n1 = fmaf(x1.w, w, n1);
            }
            ginn[0][tid] = n0; ginn[1][tid] = n1;
        } else {
            const float* wh = ws + OFF_WNH + (tid - 256);
            for (int k = 0; k < 256; k += 4) {
                float4 x0 = *(const float4*)&act[0][192 + k];
                float4 x1 = *(const float4*)&act[1][192 + k];
                float w;
                w = wh[(k + 0) * 256]; n0 = fmaf(x0.x, w, n0); n1 = fmaf(x1.x, w, n1);
                w = wh[(k + 1) * 256]; n0 = fmaf(x0.y, w, n0); n1 = fmaf(x1.y, w, n1);
                w = wh[(k + 2) * 256]; n0 = fmaf(x0.z, w, n0); n1 = fmaf(x1.z, w, n1);
                w = wh[(k + 3) * 256]; n0 = fmaf(x0.w, w, n0); n1 = fmaf(x1.w, w, n1);
            }
            ghn[0][tid - 256] = n0; ghn[1][tid - 256] = n1;
        }
        __syncthreads();

        // ---- GRU combine: group g updates row g, col lt
        {
            float r = sigf(gpre[grp][lt]);
            float z = sigf(gpre[grp][256 + lt]);
            float n = tanhf(fmaf(r, ghn[grp][lt], ginn[grp][lt]));
            float cold = act[grp][192 + lt];
            float cnew = fmaf(z, cold - n, n);
            if (t < mylen) act[grp][192 + lt] = cnew;    // frozen rows keep final ctrl
        }
        __syncthreads();

        // ---- heads: thread -> col tid of [key|erase|add|beta|pad], both rows
        float h0 = bH, h1 = bH;
        {
            const float* wh = ws + OFF_WH + tid;
            for (int k = 0; k < 256; k += 4) {
                float4 x0 = *(const float4*)&act[0][192 + k];
                float4 x1 = *(const float4*)&act[1][192 + k];
                float w;
                w = wh[(k + 0) * 512]; h0 = fmaf(x0.x, w, h0); h1 = fmaf(x1.x, w, h1);
                w = wh[(k + 1) * 512]; h0 = fmaf(x0.y, w, h0); h1 = fmaf(x1.y, w, h1);
                w = wh[(k + 2) * 512]; h0 = fmaf(x0.z, w, h0); h1 = fmaf(x1.z, w, h1);
                w = wh[(k + 3) * 512]; h0 = fmaf(x0.w, w, h0); h1 = fmaf(x1.w, w, h1);
            }
        }
        {
            int c = tid;
            if (c < 128)       { keyv[0][c] = tanhf(h0);     keyv[1][c] = tanhf(h1); }
            else if (c < 256)  { ev_s[0][c - 128] = sigf(h0); ev_s[1][c - 128] = sigf(h1); }
            else if (c < 384)  { av_s[0][c - 256] = h0;       av_s[1][c - 256] = h1; }
            else if (c == 384) { scal[0][1] = softplusf(h0);  scal[1][1] = softplusf(h1); }
        }
        __syncthreads();

        // ---- memory module: group g serves row g (identical barrier sequence)
        memory_step2(lt, t < mylen, M[grp], keyv[grp], ev_s[grp], av_s[grp],
                     cosb[grp], wb[grp], part[grp], readv[grp], scal[grp]);
    }

    {
        const int s = slot_sh[grp];
        out[(long)s * NCTRL + lt] = act[grp][192 + lt];
        if (lt < 128) out[(long)NB * NCTRL + (long)s * NWORD + lt] = readv[grp][lt];
    }
}

// FALLBACK (ws too small): round-4 verified slow path, unchanged.
__global__ __launch_bounds__(256) void ntm_slow(
    const float* __restrict__ data, const int* __restrict__ batch_sizes,
    const int* __restrict__ unsort,
    const float* __restrict__ Wih, const float* __restrict__ bih,
    const float* __restrict__ Whh, const float* __restrict__ bhh,
    const float* __restrict__ Wkey, const float* __restrict__ bkey,
    const float* __restrict__ Wbeta, const float* __restrict__ bbeta,
    const float* __restrict__ Wer, const float* __restrict__ ber,
    const float* __restrict__ Wadd, const float* __restrict__ badd,
    const float* __restrict__ M0, float* __restrict__ out)
{
    __shared__ float M[NMEM][NWORD + 1];
    __shared__ float act[NACT];
    __shared__ float ctrlB[NCTRL];
    __shared__ float gpre[512], ginn[256], ghn[256], hpre[448];
    __shared__ float readv[NWORD], keyv[NWORD], ev[NWORD], av[NWORD];
    __shared__ float cosb[NMEM], wb[NMEM], part[2 * NWORD], scal[2];
    __shared__ int len_sh;

    const int tid = threadIdx.x;
    const int g = blockIdx.x;
    const int b = unsort[g];

    if (tid == 0) {
        int L = 0;
        for (int t = 0; t < NT; ++t) L += (batch_sizes[t] > b);
        len_sh = L;
    }
    for (int i = tid; i < NMEM * NWORD; i += 256)
        M[i >> 7][i & 127] = M0[i];
    ctrlB[tid] = 0.0f;
    if (tid < NWORD) readv[tid] = 0.0f;
    __syncthreads();
    const int len = len_sh;
    const int wave = tid >> 6, lane = tid & 63;

    for (int t = 0; t < len; ++t) {
        if (tid < 64)  act[tid] = data[((long)t * NB + b) * NDIN + tid];
        if (tid < 128) act[64 + tid] = readv[tid];
        act[192 + tid] = ctrlB[tid];
        __syncthreads();

        for (int j = wave; j < 512; j += 4) {
            float p = 0.f;
            for (int k = lane; k < 192; k += 64) p = fmaf(act[k], Wih[j * 192 + k], p);
            for (int k = lane; k < 256; k += 64) p = fmaf(act[192 + k], Whh[j * 256 + k], p);
            #pragma unroll
            for (int o = 32; o >= 1; o >>= 1) p += __shfl_xor(p, o);
            if (lane == 0) gpre[j] = p;
        }
        for (int j = wave; j < 256; j += 4) {
            float pi = 0.f, ph = 0.f;
            for (int k = lane; k < 192; k += 64) pi = fmaf(act[k], Wih[(512 + j) * 192 + k], pi);
            for (int k = lane; k < 256; k += 64) ph = fmaf(act[192 + k], Whh[(512 + j) * 256 + k], ph);
            #pragma unroll
            for (int o = 32; o >= 1; o >>= 1) { pi += __shfl_xor(pi, o); ph += __shfl_xor(ph, o); }
            if (lane == 0) { ginn[j] = pi; ghn[j] = ph; }
        }
        __syncthreads();
        {
            float r = sigf(gpre[tid] + bih[tid] + bhh[tid]);
            float z = sigf(gpre[256 + tid] + bih[256 + tid] + bhh[256 + tid]);
            float inn = ginn[tid] + bih[512 + tid];
            float hn  = ghn[tid] + bhh[512 + tid];
            float n = tanhf(fmaf(r, hn, inn));
            float cold = act[192 + tid];
            ctrlB[tid] = fmaf(z, cold - n, n);
        }
        __syncthreads();
        for (int j = wave; j < 385; j += 4) {
            const float* Wp; long base;
            if (j < 128)      { Wp = Wkey;  base = (long)j * 256; }
            else if (j < 256) { Wp = Wer;   base = (long)(j - 128) * 256; }
            else if (j < 384) { Wp = Wadd;  base = (long)(j - 256) * 256; }
            else              { Wp = Wbeta; base = 0; }
            float p = 0.f;
            for (int k = lane; k < 256; k += 64) p = fmaf(ctrlB[k], Wp[base + k], p);
            #pragma unroll
            for (int o = 32; o >= 1; o >>= 1) p += __shfl_xor(p, o);
            if (lane == 0) hpre[j] = p;
        }
        __syncthreads();
        if (tid < 128) {
            keyv[tid] = tanhf(hpre[tid] + bkey[tid]);
            ev[tid]   = sigf(hpre[128 + tid] + ber[tid]);
            av[tid]   = hpre[256 + tid] + badd[tid];
        }
        if (tid == 0) scal[1] = softplusf(hpre[384] + bbeta[0]);
        __syncthreads();

        if (tid < 64) {
            float s = keyv[tid] * keyv[tid] + keyv[tid + 64] * keyv[tid + 64];
            #pragma unroll
            for (int o = 32; o >= 1; o >>= 1) s += __shfl_xor(s, o);
            if (tid == 0) scal[0] = 1.0f / (sqrtf(s) + EPSF);
        }
        __syncthreads();
        {
            int rr = tid >> 1, hh = tid & 1;
            const float* Mr = &M[rr][hh * 64];
            const float* kk = keyv + hh * 64;
            float s2 = 0.f, sc = 0.f;
            #pragma unroll 8
            for (int j = 0; j < 64; ++j) { float m = Mr[j]; s2 = fmaf(m, m, s2); sc = fmaf(m, kk[j], sc); }
            s2 += __shfl_xor(s2, 1);
            sc += __shfl_xor(sc, 1);
            if (hh == 0) cosb[rr] = sc * scal[0] / (sqrtf(s2) + EPSF);
        }
        __syncthreads();
        if (tid < 64) {
            float beta = scal[1];
            float l0 = beta * cosb[tid], l1 = beta * cosb[tid + 64];
            float mx = fmaxf(l0, l1);
            #pragma unroll
            for (int o = 32; o >= 1; o >>= 1) mx = fmaxf(mx, __shfl_xor(mx, o));
            float e0 = expf(l0 - mx), e1 = expf(l1 - mx);
            float s = e0 + e1;
            #pragma unroll
            for (int o = 32; o >= 1; o >>= 1) s += __shfl_xor(s, o);
            float inv = 1.0f / s;
            wb[tid] = e0 * inv;
            wb[tid + 64] = e1 * inv;
        }
        __syncthreads();
        {
            int j = tid & 127, hf = tid >> 7;
            float p = 0.f;
            #pragma unroll 8
            for (int r = 0; r < 64; ++r) p = fmaf(wb[hf * 64 + r], M[hf * 64 + r][j], p);
            part[hf * 128 + j] = p;
        }
        __syncthreads();
        if (tid < 128) readv[tid] = part[tid] + part[128 + tid];
        {
            int rr = tid >> 1, hh = tid & 1;
            float wr = wb[rr];
            #pragma unroll 8
            for (int i = 0; i < 64; ++i) {
                int j = hh * 64 + i;
                float m = M[rr][j];
                M[rr][j] = fmaf(-wr, fmaf(ev[j], m, -av[j]), m);
            }
        }
        __syncthreads();
    }

    out[g * NCTRL + tid] = ctrlB[tid];
    if (tid < NWORD) out[NB * NCTRL + g * NWORD + tid] = readv[tid];
}

extern "C" void kernel_launch(void* const* d_in, const int* in_sizes, int n_in,
                              void* d_out, int out_size, void* d_ws, size_t ws_size,
                              hipStream_t stream)
{
    const float* data       = (const float*)d_in[0];
    const int*  batch_sizes = (const int*)d_in[1];
    const int*  unsort      = (const int*)d_in[2];
    float* out = (float*)d_out;

    if (ws_size >= (size_t)WS_FLOATS * sizeof(float)) {
        float* ws = (float*)d_ws;
        prep_kernel<<<(WS_FLOATS + 255) / 256, 256, 0, stream>>>(
            (const float*)d_in[3], (const float*)d_in[4], (const float*)d_in[5],
            (const float*)d_in[6], (const float*)d_in[7], (const float*)d_in[8],
            (const float*)d_in[9], (const float*)d_in[10], (const float*)d_in[11],
            (const float*)d_in[12], (const float*)d_in[13], (const float*)d_in[14], ws);
        ntm2<<<NB / 2, 512, 0, stream>>>(data, batch_sizes, unsort,
                                         (const float*)d_in[15], ws, out);
    } else {
        ntm_slow<<<NB, 256, 0, stream>>>(
            data, batch_sizes, unsort,
            (const float*)d_in[3], (const float*)d_in[4], (const float*)d_in[5],
            (const float*)d_in[6], (const float*)d_in[7], (const float*)d_in[8],
            (const float*)d_in[9], (const float*)d_in[10], (const float*)d_in[11],
            (const float*)d_in[12], (const float*)d_in[13], (const float*)d_in[14],
            (const float*)d_in[15], out);
    }
}

// Round 7
// 17168.977 us; speedup vs baseline: 4.3626x; 4.3626x over previous
//
#include <hip/hip_runtime.h>
#include <math.h>

#define NB 512      // batch
#define NT 512      // time
#define NCTRL 256
#define NWORD 128
#define NMEM 128
#define NDIN 64
#define NACT 448    // x(64) | read(128) | ctrl(256)
#define EPSF 1e-6f

// fp16 weight panel layout (half-element offsets), then fp32 biases.
// Same [k][col] transposed layout as round 4, just 2-byte elements.
#define H_WA   0        // [448][512] fused r,z
#define H_WNI  229376   // [192][256] inn
#define H_WNH  278528   // [256][256] hn
#define H_WH   344064   // [256][512] heads key|erase|add|beta|pad
#define H_TOTAL 475136
#define B_BA   0        // [512] b_ih+b_hh (r,z)
#define B_BNI  512      // [256]
#define B_BNH  768      // [256]
#define B_BH   1024     // [512]
#define B_TOTAL 1536
#define WS_BYTES (H_TOTAL * 2 + B_TOTAL * 4)

__device__ __forceinline__ float sigf(float x) { return 1.0f / (1.0f + expf(-x)); }
__device__ __forceinline__ float softplusf(float x) {
    return (x > 15.0f) ? x : log1pf(expf(x));
}

__global__ __launch_bounds__(256) void prep_kernel(
    const float* __restrict__ Wih, const float* __restrict__ bih,
    const float* __restrict__ Whh, const float* __restrict__ bhh,
    const float* __restrict__ Wkey, const float* __restrict__ bkey,
    const float* __restrict__ Wbeta, const float* __restrict__ bbeta,
    const float* __restrict__ Wer, const float* __restrict__ ber,
    const float* __restrict__ Wadd, const float* __restrict__ badd,
    _Float16* __restrict__ wsH, float* __restrict__ wsB)
{
    int i = blockIdx.x * 256 + threadIdx.x;
    if (i < H_TOTAL) {
        float v;
        if (i < H_WNI) {                       // WA_T [448][512]
            int k = i >> 9, j = i & 511;
            v = (k < 192) ? Wih[j * 192 + k] : Whh[j * 256 + (k - 192)];
        } else if (i < H_WNH) {                // WNI_T [192][256]
            int i2 = i - H_WNI; int k = i2 >> 8, c = i2 & 255;
            v = Wih[(512 + c) * 192 + k];
        } else if (i < H_WH) {                 // WNH_T [256][256]
            int i2 = i - H_WNH; int k = i2 >> 8, c = i2 & 255;
            v = Whh[(512 + c) * 256 + k];
        } else {                               // WH_T [256][512]
            int i2 = i - H_WH; int k = i2 >> 9, c = i2 & 511;
            if (c < 128)       v = Wkey[c * 256 + k];
            else if (c < 256)  v = Wer[(c - 128) * 256 + k];
            else if (c < 384)  v = Wadd[(c - 256) * 256 + k];
            else if (c == 384) v = Wbeta[k];
            else               v = 0.0f;
        }
        wsH[i] = (_Float16)v;
    } else if (i < H_TOTAL + B_TOTAL) {
        int j = i - H_TOTAL;
        float v;
        if (j < 512)        v = bih[j] + bhh[j];
        else if (j < 768)   v = bih[512 + (j - 512)];
        else if (j < 1024)  v = bhh[512 + (j - 768)];
        else {
            int c = j - 1024;
            if (c < 128)       v = bkey[c];
            else if (c < 256)  v = ber[c - 128];
            else if (c < 384)  v = badd[c - 256];
            else if (c == 384) v = bbeta[0];
            else               v = 0.0f;
        }
        wsB[j] = v;
    }
}

// Shared memory module (identical to round 4 — verified).
__device__ __forceinline__ void memory_step(
    int tid, float (*M)[NWORD + 1],
    const float* keyv, const float* ev, const float* av,
    float* cosb, float* wb, float* part, float* readv, float* scal)
{
    if (tid < 64) {                       // ||k||
        float s = keyv[tid] * keyv[tid] + keyv[tid + 64] * keyv[tid + 64];
        #pragma unroll
        for (int o = 32; o >= 1; o >>= 1) s += __shfl_xor(s, o);
        if (tid == 0) scal[0] = 1.0f / (sqrtf(s) + EPSF);
    }
    __syncthreads();
    {                                      // cosine sim: 2 threads / row
        int rr = tid >> 1, hh = tid & 1;
        const float* Mr = &M[rr][hh * 64];
        const float* kk = keyv + hh * 64;
        float s2 = 0.f, sc = 0.f;
        #pragma unroll 8
        for (int j = 0; j < 64; ++j) { float m = Mr[j]; s2 = fmaf(m, m, s2); sc = fmaf(m, kk[j], sc); }
        s2 += __shfl_xor(s2, 1);
        sc += __shfl_xor(sc, 1);
        if (hh == 0) cosb[rr] = sc * scal[0] / (sqrtf(s2) + EPSF);
    }
    __syncthreads();
    if (tid < 64) {                       // softmax over 128 logits
        float beta = scal[1];
        float l0 = beta * cosb[tid], l1 = beta * cosb[tid + 64];
        float mx = fmaxf(l0, l1);
        #pragma unroll
        for (int o = 32; o >= 1; o >>= 1) mx = fmaxf(mx, __shfl_xor(mx, o));
        float e0 = expf(l0 - mx), e1 = expf(l1 - mx);
        float s = e0 + e1;
        #pragma unroll
        for (int o = 32; o >= 1; o >>= 1) s += __shfl_xor(s, o);
        float inv = 1.0f / s;
        wb[tid] = e0 * inv;
        wb[tid + 64] = e1 * inv;
    }
    __syncthreads();
    {                                      // read = w . OLD M (col-wise)
        int j = tid & 127, hf = tid >> 7;
        float p = 0.f;
        #pragma unroll 8
        for (int r = 0; r < 64; ++r) p = fmaf(wb[hf * 64 + r], M[hf * 64 + r][j], p);
        part[hf * 128 + j] = p;
    }
    __syncthreads();
    if (tid < 128) readv[tid] = part[tid] + part[128 + tid];
    {                                      // M = M - w*(e*M - a)
        int rr = tid >> 1, hh = tid & 1;
        float wr = wb[rr];
        #pragma unroll 8
        for (int i = 0; i < 64; ++i) {
            int j = hh * 64 + i;
            float m = M[rr][j];
            M[rr][j] = fmaf(-wr, fmaf(ev[j], m, -av[j]), m);
        }
    }
    __syncthreads();
}

// Round-4 structure EXACTLY (256-thr WG, 1 row, 73 KB LDS, 2 WG/CU, 512 WGs)
// — the only shape proven to keep the weight panel L2-resident. Only change:
// weights are fp16 (half the L2 bytes/step).
__global__ __launch_bounds__(256) void ntm_fast(
    const float* __restrict__ data, const int* __restrict__ batch_sizes,
    const int* __restrict__ unsort, const float* __restrict__ M0,
    const _Float16* __restrict__ wsH, const float* __restrict__ wsB,
    float* __restrict__ out)
{
    __shared__ float M[NMEM][NWORD + 1];
    __shared__ float actA[NACT];
    __shared__ float ctrlB[NCTRL];
    __shared__ float readv[NWORD], keyv[NWORD], ev[NWORD], av[NWORD];
    __shared__ float cosb[NMEM], wb[NMEM], part[2 * NWORD], scal[2];
    __shared__ int len_sh;

    const int tid = threadIdx.x;
    const int g = blockIdx.x;
    const int b = unsort[g];

    if (tid == 0) {
        int L = 0;
        for (int t = 0; t < NT; ++t) L += (batch_sizes[t] > b);
        len_sh = L;
    }
    for (int i = tid; i < NMEM * NWORD; i += 256)
        M[i >> 7][i & 127] = M0[i];
    ctrlB[tid] = 0.0f;
    if (tid < NWORD) readv[tid] = 0.0f;
    __syncthreads();
    const int len = len_sh;

    const float bA0 = wsB[B_BA + tid],  bA1 = wsB[B_BA + 256 + tid];
    const float bNi = wsB[B_BNI + tid], bNh = wsB[B_BNH + tid];
    const float bH0 = wsB[B_BH + tid],  bH1 = wsB[B_BH + 256 + tid];

    for (int t = 0; t < len; ++t) {
        if (tid < 64)  actA[tid] = data[((long)t * NB + b) * NDIN + tid];
        if (tid < 128) actA[64 + tid] = readv[tid];
        actA[192 + tid] = ctrlB[tid];       // old ctrl copy
        __syncthreads();

        float a0 = bA0, a1 = bA1;           // r (col tid), z (col tid+256)
        {
            const _Float16* wa = wsH + H_WA + tid;
            #pragma unroll 8
            for (int k = 0; k < 448; ++k) {
                float v = actA[k];
                a0 = fmaf(v, (float)wa[0], a0);
                a1 = fmaf(v, (float)wa[256], a1);
                wa += 512;
            }
        }
        float ai = bNi, ah = bNh;           // inn, hn
        {
            const _Float16* w = wsH + H_WNI + tid;
            #pragma unroll 8
            for (int k = 0; k < 192; ++k) { ai = fmaf(actA[k], (float)w[0], ai); w += 256; }
        }
        {
            const _Float16* w = wsH + H_WNH + tid;
            #pragma unroll 8
            for (int k = 0; k < 256; ++k) { ah = fmaf(actA[192 + k], (float)w[0], ah); w += 256; }
        }
        float rg = sigf(a0), zg = sigf(a1);
        float ng = tanhf(fmaf(rg, ah, ai));
        float cold = actA[192 + tid];
        ctrlB[tid] = fmaf(zg, cold - ng, ng);
        __syncthreads();

        float h0 = bH0, h1 = bH1;           // head cols tid, tid+256
        {
            const _Float16* wh = wsH + H_WH + tid;
            #pragma unroll 8
            for (int k = 0; k < 256; ++k) {
                float v = ctrlB[k];
                h0 = fmaf(v, (float)wh[0], h0);
                h1 = fmaf(v, (float)wh[256], h1);
                wh += 512;
            }
        }
        if (tid < 128) { keyv[tid] = tanhf(h0); av[tid] = h1; }
        else           { ev[tid - 128] = sigf(h0); }
        if (tid == 128) scal[1] = softplusf(h1);   // col 384 = beta
        __syncthreads();

        memory_step(tid, M, keyv, ev, av, cosb, wb, part, readv, scal);
    }

    out[g * NCTRL + tid] = ctrlB[tid];
    if (tid < NWORD) out[NB * NCTRL + g * NWORD + tid] = readv[tid];
}

// FALLBACK (ws too small): round-4 verified slow path, unchanged.
__global__ __launch_bounds__(256) void ntm_slow(
    const float* __restrict__ data, const int* __restrict__ batch_sizes,
    const int* __restrict__ unsort,
    const float* __restrict__ Wih, const float* __restrict__ bih,
    const float* __restrict__ Whh, const float* __restrict__ bhh,
    const float* __restrict__ Wkey, const float* __restrict__ bkey,
    const float* __restrict__ Wbeta, const float* __restrict__ bbeta,
    const float* __restrict__ Wer, const float* __restrict__ ber,
    const float* __restrict__ Wadd, const float* __restrict__ badd,
    const float* __restrict__ M0, float* __restrict__ out)
{
    __shared__ float M[NMEM][NWORD + 1];
    __shared__ float act[NACT];
    __shared__ float ctrlB[NCTRL];
    __shared__ float gpre[512], ginn[256], ghn[256], hpre[448];
    __shared__ float readv[NWORD], keyv[NWORD], ev[NWORD], av[NWORD];
    __shared__ float cosb[NMEM], wb[NMEM], part[2 * NWORD], scal[2];
    __shared__ int len_sh;

    const int tid = threadIdx.x;
    const int g = blockIdx.x;
    const int b = unsort[g];

    if (tid == 0) {
        int L = 0;
        for (int t = 0; t < NT; ++t) L += (batch_sizes[t] > b);
        len_sh = L;
    }
    for (int i = tid; i < NMEM * NWORD; i += 256)
        M[i >> 7][i & 127] = M0[i];
    ctrlB[tid] = 0.0f;
    if (tid < NWORD) readv[tid] = 0.0f;
    __syncthreads();
    const int len = len_sh;
    const int wave = tid >> 6, lane = tid & 63;

    for (int t = 0; t < len; ++t) {
        if (tid < 64)  act[tid] = data[((long)t * NB + b) * NDIN + tid];
        if (tid < 128) act[64 + tid] = readv[tid];
        act[192 + tid] = ctrlB[tid];
        __syncthreads();

        for (int j = wave; j < 512; j += 4) {
            float p = 0.f;
            for (int k = lane; k < 192; k += 64) p = fmaf(act[k], Wih[j * 192 + k], p);
            for (int k = lane; k < 256; k += 64) p = fmaf(act[192 + k], Whh[j * 256 + k], p);
            #pragma unroll
            for (int o = 32; o >= 1; o >>= 1) p += __shfl_xor(p, o);
            if (lane == 0) gpre[j] = p;
        }
        for (int j = wave; j < 256; j += 4) {
            float pi = 0.f, ph = 0.f;
            for (int k = lane; k < 192; k += 64) pi = fmaf(act[k], Wih[(512 + j) * 192 + k], pi);
            for (int k = lane; k < 256; k += 64) ph = fmaf(act[192 + k], Whh[(512 + j) * 256 + k], ph);
            #pragma unroll
            for (int o = 32; o >= 1; o >>= 1) { pi += __shfl_xor(pi, o); ph += __shfl_xor(ph, o); }
            if (lane == 0) { ginn[j] = pi; ghn[j] = ph; }
        }
        __syncthreads();
        {
            float r = sigf(gpre[tid] + bih[tid] + bhh[tid]);
            float z = sigf(gpre[256 + tid] + bih[256 + tid] + bhh[256 + tid]);
            float inn = ginn[tid] + bih[512 + tid];
            float hn  = ghn[tid] + bhh[512 + tid];
            float n = tanhf(fmaf(r, hn, inn));
            float cold = act[192 + tid];
            ctrlB[tid] = fmaf(z, cold - n, n);
        }
        __syncthreads();
        for (int j = wave; j < 385; j += 4) {
            const float* Wp; long base;
            if (j < 128)      { Wp = Wkey;  base = (long)j * 256; }
            else if (j < 256) { Wp = Wer;   base = (long)(j - 128) * 256; }
            else if (j < 384) { Wp = Wadd;  base = (long)(j - 256) * 256; }
            else              { Wp = Wbeta; base = 0; }
            float p = 0.f;
            for (int k = lane; k < 256; k += 64) p = fmaf(ctrlB[k], Wp[base + k], p);
            #pragma unroll
            for (int o = 32; o >= 1; o >>= 1) p += __shfl_xor(p, o);
            if (lane == 0) hpre[j] = p;
        }
        __syncthreads();
        if (tid < 128) {
            keyv[tid] = tanhf(hpre[tid] + bkey[tid]);
            ev[tid]   = sigf(hpre[128 + tid] + ber[tid]);
            av[tid]   = hpre[256 + tid] + badd[tid];
        }
        if (tid == 0) scal[1] = softplusf(hpre[384] + bbeta[0]);
        __syncthreads();

        memory_step(tid, M, keyv, ev, av, cosb, wb, part, readv, scal);
    }

    out[g * NCTRL + tid] = ctrlB[tid];
    if (tid < NWORD) out[NB * NCTRL + g * NWORD + tid] = readv[tid];
}

extern "C" void kernel_launch(void* const* d_in, const int* in_sizes, int n_in,
                              void* d_out, int out_size, void* d_ws, size_t ws_size,
                              hipStream_t stream)
{
    const float* data       = (const float*)d_in[0];
    const int*  batch_sizes = (const int*)d_in[1];
    const int*  unsort      = (const int*)d_in[2];
    float* out = (float*)d_out;

    if (ws_size >= (size_t)WS_BYTES) {
        _Float16* wsH = (_Float16*)d_ws;
        float* wsB = (float*)((char*)d_ws + (size_t)H_TOTAL * 2);
        prep_kernel<<<(H_TOTAL + B_TOTAL + 255) / 256, 256, 0, stream>>>(
            (const float*)d_in[3], (const float*)d_in[4], (const float*)d_in[5],
            (const float*)d_in[6], (const float*)d_in[7], (const float*)d_in[8],
            (const float*)d_in[9], (const float*)d_in[10], (const float*)d_in[11],
            (const float*)d_in[12], (const float*)d_in[13], (const float*)d_in[14],
            wsH, wsB);
        ntm_fast<<<NB, 256, 0, stream>>>(data, batch_sizes, unsort,
                                         (const float*)d_in[15], wsH, wsB, out);
    } else {
        ntm_slow<<<NB, 256, 0, stream>>>(
            data, batch_sizes, unsort,
            (const float*)d_in[3], (const float*)d_in[4], (const float*)d_in[5],
            (const float*)d_in[6], (const float*)d_in[7], (const float*)d_in[8],
            (const float*)d_in[9], (const float*)d_in[10], (const float*)d_in[11],
            (const float*)d_in[12], (const float*)d_in[13], (const float*)d_in[14],
            (const float*)d_in[15], out);
    }
}

// Round 8
// 11867.339 us; speedup vs baseline: 6.3116x; 1.4467x over previous
//
#include <hip/hip_runtime.h>
#include <math.h>

#define NB 512      // batch
#define NT 512      // time
#define NCTRL 256
#define NWORD 128
#define NMEM 128
#define NDIN 64
#define NACT 448    // x(64) | read(128) | ctrl(256)
#define EPSF 1e-6f

// fp16 weight panel, CHUNK-TRANSPOSED layout: 16-byte chunks of 8 consecutive
// k, interleaved by column so a wave's lanes read consecutive 16B chunks.
//   element(region, kc, col, e)  at  region_base + (kc*NCOLS + col)*8 + e
// Half-element offsets (same totals as the flat layout):
#define H_WA   0        // rz:    56 kc x 512 cols x 8
#define H_WNI  229376   // inn:   24 kc x 256 cols x 8
#define H_WNH  278528   // hn:    32 kc x 256 cols x 8
#define H_WH   344064   // heads: 32 kc x 512 cols x 8 (key|erase|add|beta|pad)
#define H_TOTAL 475136
#define B_BA   0        // [512] b_ih+b_hh (r,z)
#define B_BNI  512      // [256]
#define B_BNH  768      // [256]
#define B_BH   1024     // [512]
#define B_TOTAL 1536
#define WS_BYTES (H_TOTAL * 2 + B_TOTAL * 4)

typedef _Float16 half8 __attribute__((ext_vector_type(8)));

__device__ __forceinline__ float sigf(float x) { return 1.0f / (1.0f + expf(-x)); }
__device__ __forceinline__ float softplusf(float x) {
    return (x > 15.0f) ? x : log1pf(expf(x));
}

// 8 fmas for two columns, split accumulators (a=e0..3, b=e4..7) for ILP.
__device__ __forceinline__ void fma8_2(half8 w0, half8 w1, float4 xlo, float4 xhi,
                                       float& a0, float& a1, float& b0, float& b1)
{
    a0 = fmaf(xlo.x, (float)w0[0], a0); a1 = fmaf(xlo.x, (float)w1[0], a1);
    a0 = fmaf(xlo.y, (float)w0[1], a0); a1 = fmaf(xlo.y, (float)w1[1], a1);
    a0 = fmaf(xlo.z, (float)w0[2], a0); a1 = fmaf(xlo.z, (float)w1[2], a1);
    a0 = fmaf(xlo.w, (float)w0[3], a0); a1 = fmaf(xlo.w, (float)w1[3], a1);
    b0 = fmaf(xhi.x, (float)w0[4], b0); b1 = fmaf(xhi.x, (float)w1[4], b1);
    b0 = fmaf(xhi.y, (float)w0[5], b0); b1 = fmaf(xhi.y, (float)w1[5], b1);
    b0 = fmaf(xhi.z, (float)w0[6], b0); b1 = fmaf(xhi.z, (float)w1[6], b1);
    b0 = fmaf(xhi.w, (float)w0[7], b0); b1 = fmaf(xhi.w, (float)w1[7], b1);
}
__device__ __forceinline__ void fma8_1(half8 w, float4 xlo, float4 xhi,
                                       float& a, float& b)
{
    a = fmaf(xlo.x, (float)w[0], a);
    a = fmaf(xlo.y, (float)w[1], a);
    a = fmaf(xlo.z, (float)w[2], a);
    a = fmaf(xlo.w, (float)w[3], a);
    b = fmaf(xhi.x, (float)w[4], b);
    b = fmaf(xhi.y, (float)w[5], b);
    b = fmaf(xhi.z, (float)w[6], b);
    b = fmaf(xhi.w, (float)w[7], b);
}

__global__ __launch_bounds__(256) void prep_kernel(
    const float* __restrict__ Wih, const float* __restrict__ bih,
    const float* __restrict__ Whh, const float* __restrict__ bhh,
    const float* __restrict__ Wkey, const float* __restrict__ bkey,
    const float* __restrict__ Wbeta, const float* __restrict__ bbeta,
    const float* __restrict__ Wer, const float* __restrict__ ber,
    const float* __restrict__ Wadd, const float* __restrict__ badd,
    _Float16* __restrict__ wsH, float* __restrict__ wsB)
{
    int i = blockIdx.x * 256 + threadIdx.x;
    if (i < H_TOTAL) {
        float v;
        if (i < H_WNI) {                       // rz [kc][512][8]
            int ch = i >> 3, e = i & 7;
            int kc = ch >> 9, col = ch & 511;
            int k = kc * 8 + e;
            v = (k < 192) ? Wih[col * 192 + k] : Whh[col * 256 + (k - 192)];
        } else if (i < H_WNH) {                // inn [kc][256][8], k<192
            int i2 = i - H_WNI; int ch = i2 >> 3, e = i2 & 7;
            int kc = ch >> 8, col = ch & 255;
            v = Wih[(512 + col) * 192 + kc * 8 + e];
        } else if (i < H_WH) {                 // hn [kc][256][8], k<256
            int i2 = i - H_WNH; int ch = i2 >> 3, e = i2 & 7;
            int kc = ch >> 8, col = ch & 255;
            v = Whh[(512 + col) * 256 + kc * 8 + e];
        } else {                               // heads [kc][512][8], k<256
            int i2 = i - H_WH; int ch = i2 >> 3, e = i2 & 7;
            int kc = ch >> 9, col = ch & 511;
            int k = kc * 8 + e;
            if (col < 128)       v = Wkey[col * 256 + k];
            else if (col < 256)  v = Wer[(col - 128) * 256 + k];
            else if (col < 384)  v = Wadd[(col - 256) * 256 + k];
            else if (col == 384) v = Wbeta[k];
            else                 v = 0.0f;
        }
        wsH[i] = (_Float16)v;
    } else if (i < H_TOTAL + B_TOTAL) {
        int j = i - H_TOTAL;
        float v;
        if (j < 512)        v = bih[j] + bhh[j];
        else if (j < 768)   v = bih[512 + (j - 512)];
        else if (j < 1024)  v = bhh[512 + (j - 768)];
        else {
            int c = j - 1024;
            if (c < 128)       v = bkey[c];
            else if (c < 256)  v = ber[c - 128];
            else if (c < 384)  v = badd[c - 256];
            else if (c == 384) v = bbeta[0];
            else               v = 0.0f;
        }
        wsB[j] = v;
    }
}

// Shared memory module (identical to round 4 — verified).
__device__ __forceinline__ void memory_step(
    int tid, float (*M)[NWORD + 1],
    const float* keyv, const float* ev, const float* av,
    float* cosb, float* wb, float* part, float* readv, float* scal)
{
    if (tid < 64) {                       // ||k||
        float s = keyv[tid] * keyv[tid] + keyv[tid + 64] * keyv[tid + 64];
        #pragma unroll
        for (int o = 32; o >= 1; o >>= 1) s += __shfl_xor(s, o);
        if (tid == 0) scal[0] = 1.0f / (sqrtf(s) + EPSF);
    }
    __syncthreads();
    {                                      // cosine sim: 2 threads / row
        int rr = tid >> 1, hh = tid & 1;
        const float* Mr = &M[rr][hh * 64];
        const float* kk = keyv + hh * 64;
        float s2 = 0.f, sc = 0.f;
        #pragma unroll 8
        for (int j = 0; j < 64; ++j) { float m = Mr[j]; s2 = fmaf(m, m, s2); sc = fmaf(m, kk[j], sc); }
        s2 += __shfl_xor(s2, 1);
        sc += __shfl_xor(sc, 1);
        if (hh == 0) cosb[rr] = sc * scal[0] / (sqrtf(s2) + EPSF);
    }
    __syncthreads();
    if (tid < 64) {                       // softmax over 128 logits
        float beta = scal[1];
        float l0 = beta * cosb[tid], l1 = beta * cosb[tid + 64];
        float mx = fmaxf(l0, l1);
        #pragma unroll
        for (int o = 32; o >= 1; o >>= 1) mx = fmaxf(mx, __shfl_xor(mx, o));
        float e0 = expf(l0 - mx), e1 = expf(l1 - mx);
        float s = e0 + e1;
        #pragma unroll
        for (int o = 32; o >= 1; o >>= 1) s += __shfl_xor(s, o);
        float inv = 1.0f / s;
        wb[tid] = e0 * inv;
        wb[tid + 64] = e1 * inv;
    }
    __syncthreads();
    {                                      // read = w . OLD M (col-wise)
        int j = tid & 127, hf = tid >> 7;
        float p = 0.f;
        #pragma unroll 8
        for (int r = 0; r < 64; ++r) p = fmaf(wb[hf * 64 + r], M[hf * 64 + r][j], p);
        part[hf * 128 + j] = p;
    }
    __syncthreads();
    if (tid < 128) readv[tid] = part[tid] + part[128 + tid];
    {                                      // M = M - w*(e*M - a)
        int rr = tid >> 1, hh = tid & 1;
        float wr = wb[rr];
        #pragma unroll 8
        for (int i = 0; i < 64; ++i) {
            int j = hh * 64 + i;
            float m = M[rr][j];
            M[rr][j] = fmaf(-wr, fmaf(ev[j], m, -av[j]), m);
        }
    }
    __syncthreads();
}

// Round-4 shape EXACTLY (256-thr WG, 1 row, 73 KB LDS, 2 WG/CU, 512 WGs).
// Only change vs round 7: chunk-transposed fp16 panel -> 16B coalesced
// weight loads (8x fewer VMEM instructions).
__global__ __launch_bounds__(256) void ntm_fast(
    const float* __restrict__ data, const int* __restrict__ batch_sizes,
    const int* __restrict__ unsort, const float* __restrict__ M0,
    const _Float16* __restrict__ wsH, const float* __restrict__ wsB,
    float* __restrict__ out)
{
    __shared__ float M[NMEM][NWORD + 1];
    __shared__ __align__(16) float actA[NACT];
    __shared__ __align__(16) float ctrlB[NCTRL];
    __shared__ float readv[NWORD], keyv[NWORD], ev[NWORD], av[NWORD];
    __shared__ float cosb[NMEM], wb[NMEM], part[2 * NWORD], scal[2];
    __shared__ int len_sh;

    const int tid = threadIdx.x;
    const int g = blockIdx.x;
    const int b = unsort[g];

    if (tid == 0) {
        int L = 0;
        for (int t = 0; t < NT; ++t) L += (batch_sizes[t] > b);
        len_sh = L;
    }
    for (int i = tid; i < NMEM * NWORD; i += 256)
        M[i >> 7][i & 127] = M0[i];
    ctrlB[tid] = 0.0f;
    if (tid < NWORD) readv[tid] = 0.0f;
    __syncthreads();
    const int len = len_sh;

    const float bA0 = wsB[B_BA + tid],  bA1 = wsB[B_BA + 256 + tid];
    const float bNi = wsB[B_BNI + tid], bNh = wsB[B_BNH + tid];
    const float bH0 = wsB[B_BH + tid],  bH1 = wsB[B_BH + 256 + tid];

    const half8* __restrict__ pA  = (const half8*)(wsH + H_WA);
    const half8* __restrict__ pI  = (const half8*)(wsH + H_WNI);
    const half8* __restrict__ pH  = (const half8*)(wsH + H_WNH);
    const half8* __restrict__ pHD = (const half8*)(wsH + H_WH);
    const float4* act4  = (const float4*)actA;
    const float4* ctrl4 = (const float4*)ctrlB;

    for (int t = 0; t < len; ++t) {
        if (tid < 64)  actA[tid] = data[((long)t * NB + b) * NDIN + tid];
        if (tid < 128) actA[64 + tid] = readv[tid];
        actA[192 + tid] = ctrlB[tid];       // old ctrl copy
        __syncthreads();

        // ---- fused r,z: cols (tid, tid+256), 56 chunks over act[0..447]
        float a0 = bA0, a1 = bA1, c0 = 0.f, c1 = 0.f;
        #pragma unroll 4
        for (int kc = 0; kc < 56; ++kc) {
            half8 w0 = pA[kc * 512 + tid];
            half8 w1 = pA[kc * 512 + tid + 256];
            fma8_2(w0, w1, act4[kc * 2], act4[kc * 2 + 1], a0, a1, c0, c1);
        }
        a0 += c0; a1 += c1;
        // ---- inn: col tid, 24 chunks over act[0..191]
        float ai = bNi, ci = 0.f;
        #pragma unroll 4
        for (int kc = 0; kc < 24; ++kc)
            fma8_1(pI[kc * 256 + tid], act4[kc * 2], act4[kc * 2 + 1], ai, ci);
        ai += ci;
        // ---- hn: col tid, 32 chunks over act[192..447]
        float ah = bNh, ch = 0.f;
        #pragma unroll 4
        for (int kc = 0; kc < 32; ++kc)
            fma8_1(pH[kc * 256 + tid], act4[48 + kc * 2], act4[48 + kc * 2 + 1], ah, ch);
        ah += ch;

        float rg = sigf(a0), zg = sigf(a1);
        float ng = tanhf(fmaf(rg, ah, ai));
        float cold = actA[192 + tid];
        ctrlB[tid] = fmaf(zg, cold - ng, ng);
        __syncthreads();

        // ---- heads: cols (tid, tid+256), 32 chunks over ctrl[0..255]
        float h0 = bH0, h1 = bH1, d0 = 0.f, d1 = 0.f;
        #pragma unroll 4
        for (int kc = 0; kc < 32; ++kc) {
            half8 w0 = pHD[kc * 512 + tid];
            half8 w1 = pHD[kc * 512 + tid + 256];
            fma8_2(w0, w1, ctrl4[kc * 2], ctrl4[kc * 2 + 1], h0, h1, d0, d1);
        }
        h0 += d0; h1 += d1;

        if (tid < 128) { keyv[tid] = tanhf(h0); av[tid] = h1; }
        else           { ev[tid - 128] = sigf(h0); }
        if (tid == 128) scal[1] = softplusf(h1);   // col 384 = beta
        __syncthreads();

        memory_step(tid, M, keyv, ev, av, cosb, wb, part, readv, scal);
    }

    out[g * NCTRL + tid] = ctrlB[tid];
    if (tid < NWORD) out[NB * NCTRL + g * NWORD + tid] = readv[tid];
}

// FALLBACK (ws too small): round-4 verified slow path, unchanged.
__global__ __launch_bounds__(256) void ntm_slow(
    const float* __restrict__ data, const int* __restrict__ batch_sizes,
    const int* __restrict__ unsort,
    const float* __restrict__ Wih, const float* __restrict__ bih,
    const float* __restrict__ Whh, const float* __restrict__ bhh,
    const float* __restrict__ Wkey, const float* __restrict__ bkey,
    const float* __restrict__ Wbeta, const float* __restrict__ bbeta,
    const float* __restrict__ Wer, const float* __restrict__ ber,
    const float* __restrict__ Wadd, const float* __restrict__ badd,
    const float* __restrict__ M0, float* __restrict__ out)
{
    __shared__ float M[NMEM][NWORD + 1];
    __shared__ float act[NACT];
    __shared__ float ctrlB[NCTRL];
    __shared__ float gpre[512], ginn[256], ghn[256], hpre[448];
    __shared__ float readv[NWORD], keyv[NWORD], ev[NWORD], av[NWORD];
    __shared__ float cosb[NMEM], wb[NMEM], part[2 * NWORD], scal[2];
    __shared__ int len_sh;

    const int tid = threadIdx.x;
    const int g = blockIdx.x;
    const int b = unsort[g];

    if (tid == 0) {
        int L = 0;
        for (int t = 0; t < NT; ++t) L += (batch_sizes[t] > b);
        len_sh = L;
    }
    for (int i = tid; i < NMEM * NWORD; i += 256)
        M[i >> 7][i & 127] = M0[i];
    ctrlB[tid] = 0.0f;
    if (tid < NWORD) readv[tid] = 0.0f;
    __syncthreads();
    const int len = len_sh;
    const int wave = tid >> 6, lane = tid & 63;

    for (int t = 0; t < len; ++t) {
        if (tid < 64)  act[tid] = data[((long)t * NB + b) * NDIN + tid];
        if (tid < 128) act[64 + tid] = readv[tid];
        act[192 + tid] = ctrlB[tid];
        __syncthreads();

        for (int j = wave; j < 512; j += 4) {
            float p = 0.f;
            for (int k = lane; k < 192; k += 64) p = fmaf(act[k], Wih[j * 192 + k], p);
            for (int k = lane; k < 256; k += 64) p = fmaf(act[192 + k], Whh[j * 256 + k], p);
            #pragma unroll
            for (int o = 32; o >= 1; o >>= 1) p += __shfl_xor(p, o);
            if (lane == 0) gpre[j] = p;
        }
        for (int j = wave; j < 256; j += 4) {
            float pi = 0.f, ph = 0.f;
            for (int k = lane; k < 192; k += 64) pi = fmaf(act[k], Wih[(512 + j) * 192 + k], pi);
            for (int k = lane; k < 256; k += 64) ph = fmaf(act[192 + k], Whh[(512 + j) * 256 + k], ph);
            #pragma unroll
            for (int o = 32; o >= 1; o >>= 1) { pi += __shfl_xor(pi, o); ph += __shfl_xor(ph, o); }
            if (lane == 0) { ginn[j] = pi; ghn[j] = ph; }
        }
        __syncthreads();
        {
            float r = sigf(gpre[tid] + bih[tid] + bhh[tid]);
            float z = sigf(gpre[256 + tid] + bih[256 + tid] + bhh[256 + tid]);
            float inn = ginn[tid] + bih[512 + tid];
            float hn  = ghn[tid] + bhh[512 + tid];
            float n = tanhf(fmaf(r, hn, inn));
            float cold = act[192 + tid];
            ctrlB[tid] = fmaf(z, cold - n, n);
        }
        __syncthreads();
        for (int j = wave; j < 385; j += 4) {
            const float* Wp; long base;
            if (j < 128)      { Wp = Wkey;  base = (long)j * 256; }
            else if (j < 256) { Wp = Wer;   base = (long)(j - 128) * 256; }
            else if (j < 384) { Wp = Wadd;  base = (long)(j - 256) * 256; }
            else              { Wp = Wbeta; base = 0; }
            float p = 0.f;
            for (int k = lane; k < 256; k += 64) p = fmaf(ctrlB[k], Wp[base + k], p);
            #pragma unroll
            for (int o = 32; o >= 1; o >>= 1) p += __shfl_xor(p, o);
            if (lane == 0) hpre[j] = p;
        }
        __syncthreads();
        if (tid < 128) {
            keyv[tid] = tanhf(hpre[tid] + bkey[tid]);
            ev[tid]   = sigf(hpre[128 + tid] + ber[tid]);
            av[tid]   = hpre[256 + tid] + badd[tid];
        }
        if (tid == 0) scal[1] = softplusf(hpre[384] + bbeta[0]);
        __syncthreads();

        memory_step(tid, M, keyv, ev, av, cosb, wb, part, readv, scal);
    }

    out[g * NCTRL + tid] = ctrlB[tid];
    if (tid < NWORD) out[NB * NCTRL + g * NWORD + tid] = readv[tid];
}

extern "C" void kernel_launch(void* const* d_in, const int* in_sizes, int n_in,
                              void* d_out, int out_size, void* d_ws, size_t ws_size,
                              hipStream_t stream)
{
    const float* data       = (const float*)d_in[0];
    const int*  batch_sizes = (const int*)d_in[1];
    const int*  unsort      = (const int*)d_in[2];
    float* out = (float*)d_out;

    if (ws_size >= (size_t)WS_BYTES) {
        _Float16* wsH = (_Float16*)d_ws;
        float* wsB = (float*)((char*)d_ws + (size_t)H_TOTAL * 2);
        prep_kernel<<<(H_TOTAL + B_TOTAL + 255) / 256, 256, 0, stream>>>(
            (const float*)d_in[3], (const float*)d_in[4], (const float*)d_in[5],
            (const float*)d_in[6], (const float*)d_in[7], (const float*)d_in[8],
            (const float*)d_in[9], (const float*)d_in[10], (const float*)d_in[11],
            (const float*)d_in[12], (const float*)d_in[13], (const float*)d_in[14],
            wsH, wsB);
        ntm_fast<<<NB, 256, 0, stream>>>(data, batch_sizes, unsort,
                                         (const float*)d_in[15], wsH, wsB, out);
    } else {
        ntm_slow<<<NB, 256, 0, stream>>>(
            data, batch_sizes, unsort,
            (const float*)d_in[3], (const float*)d_in[4], (const float*)d_in[5],
            (const float*)d_in[6], (const float*)d_in[7], (const float*)d_in[8],
            (const float*)d_in[9], (const float*)d_in[10], (const float*)d_in[11],
            (const float*)d_in[12], (const float*)d_in[13], (const float*)d_in[14],
            (const float*)d_in[15], out);
    }
}

// Round 9
// 8502.714 us; speedup vs baseline: 8.8092x; 1.3957x over previous
//
#include <hip/hip_runtime.h>
#include <math.h>

#define NB 512      // batch
#define NT 512      // time
#define NCTRL 256
#define NWORD 128
#define NMEM 128
#define NDIN 64
#define NACT 448    // x(64) | read(128) | ctrl(256)
#define EPSF 1e-6f

// fp16 weight panel, CHUNK-TRANSPOSED layout (identical to round 8):
//   element(region, kc, col, e) at region_base + (kc*NCOLS + col)*8 + e
#define H_WA   0        // rz:    56 kc x 512 cols x 8
#define H_WNI  229376   // inn:   24 kc x 256 cols x 8
#define H_WNH  278528   // hn:    32 kc x 256 cols x 8
#define H_WH   344064   // heads: 32 kc x 512 cols x 8 (key|erase|add|beta|pad)
#define H_TOTAL 475136
#define B_BA   0        // [512] b_ih+b_hh (r,z)
#define B_BNI  512      // [256]
#define B_BNH  768      // [256]
#define B_BH   1024     // [512]
#define B_TOTAL 1536
#define WS_BYTES (H_TOTAL * 2 + B_TOTAL * 4)

typedef _Float16 h2 __attribute__((ext_vector_type(2)));
typedef _Float16 h8 __attribute__((ext_vector_type(8)));
union H8 { h8 v; h2 d[4]; };

__device__ __forceinline__ float sigf(float x) { return 1.0f / (1.0f + expf(-x)); }
__device__ __forceinline__ float softplusf(float x) {
    return (x > 15.0f) ? x : log1pf(expf(x));
}
__device__ __forceinline__ float fdot2(h2 a, h2 b, float c) {
#if __has_builtin(__builtin_amdgcn_fdot2)
    return __builtin_amdgcn_fdot2(a, b, c, false);
#else
    return fmaf((float)a[0], (float)b[0], fmaf((float)a[1], (float)b[1], c));
#endif
}

__global__ __launch_bounds__(256) void prep_kernel(
    const float* __restrict__ Wih, const float* __restrict__ bih,
    const float* __restrict__ Whh, const float* __restrict__ bhh,
    const float* __restrict__ Wkey, const float* __restrict__ bkey,
    const float* __restrict__ Wbeta, const float* __restrict__ bbeta,
    const float* __restrict__ Wer, const float* __restrict__ ber,
    const float* __restrict__ Wadd, const float* __restrict__ badd,
    _Float16* __restrict__ wsH, float* __restrict__ wsB)
{
    int i = blockIdx.x * 256 + threadIdx.x;
    if (i < H_TOTAL) {
        float v;
        if (i < H_WNI) {                       // rz [kc][512][8]
            int ch = i >> 3, e = i & 7;
            int kc = ch >> 9, col = ch & 511;
            int k = kc * 8 + e;
            v = (k < 192) ? Wih[col * 192 + k] : Whh[col * 256 + (k - 192)];
        } else if (i < H_WNH) {                // inn [kc][256][8], k<192
            int i2 = i - H_WNI; int ch = i2 >> 3, e = i2 & 7;
            int kc = ch >> 8, col = ch & 255;
            v = Wih[(512 + col) * 192 + kc * 8 + e];
        } else if (i < H_WH) {                 // hn [kc][256][8], k<256
            int i2 = i - H_WNH; int ch = i2 >> 3, e = i2 & 7;
            int kc = ch >> 8, col = ch & 255;
            v = Whh[(512 + col) * 256 + kc * 8 + e];
        } else {                               // heads [kc][512][8], k<256
            int i2 = i - H_WH; int ch = i2 >> 3, e = i2 & 7;
            int kc = ch >> 9, col = ch & 511;
            int k = kc * 8 + e;
            if (col < 128)       v = Wkey[col * 256 + k];
            else if (col < 256)  v = Wer[(col - 128) * 256 + k];
            else if (col < 384)  v = Wadd[(col - 256) * 256 + k];
            else if (col == 384) v = Wbeta[k];
            else                 v = 0.0f;
        }
        wsH[i] = (_Float16)v;
    } else if (i < H_TOTAL + B_TOTAL) {
        int j = i - H_TOTAL;
        float v;
        if (j < 512)        v = bih[j] + bhh[j];
        else if (j < 768)   v = bih[512 + (j - 512)];
        else if (j < 1024)  v = bhh[512 + (j - 768)];
        else {
            int c = j - 1024;
            if (c < 128)       v = bkey[c];
            else if (c < 256)  v = ber[c - 128];
            else if (c < 384)  v = badd[c - 256];
            else if (c == 384) v = bbeta[0];
            else               v = 0.0f;
        }
        wsB[j] = v;
    }
}

// Memory module v2: same barrier skeleton as the verified round-4 version,
// but read+update fused into one column-oriented M pass, and kk/wb preloaded
// as float4. Reads OLD M for cos+read, then updates M in place.
__device__ __forceinline__ void memory_step(
    int tid, float (*M)[NWORD + 1],
    const float* keyv, const float* ev, const float* av,
    float* cosb, float* wb, float* part, float* readv, float* scal)
{
    if (tid < 64) {                       // ||k||
        float s = keyv[tid] * keyv[tid] + keyv[tid + 64] * keyv[tid + 64];
        #pragma unroll
        for (int o = 32; o >= 1; o >>= 1) s += __shfl_xor(s, o);
        if (tid == 0) scal[0] = 1.0f / (sqrtf(s) + EPSF);
    }
    __syncthreads();
    {                                      // cosine sim: 2 threads / row
        int rr = tid >> 1, hh = tid & 1;
        const float* Mr = &M[rr][hh * 64];
        const float4* kk4 = (const float4*)(keyv + hh * 64);
        float s2 = 0.f, sc = 0.f;
        #pragma unroll
        for (int q = 0; q < 16; ++q) {
            float4 k4 = kk4[q];
            float m0 = Mr[4 * q], m1 = Mr[4 * q + 1], m2 = Mr[4 * q + 2], m3 = Mr[4 * q + 3];
            s2 = fmaf(m0, m0, s2); sc = fmaf(m0, k4.x, sc);
            s2 = fmaf(m1, m1, s2); sc = fmaf(m1, k4.y, sc);
            s2 = fmaf(m2, m2, s2); sc = fmaf(m2, k4.z, sc);
            s2 = fmaf(m3, m3, s2); sc = fmaf(m3, k4.w, sc);
        }
        s2 += __shfl_xor(s2, 1);
        sc += __shfl_xor(sc, 1);
        if (hh == 0) cosb[rr] = sc * scal[0] / (sqrtf(s2) + EPSF);
    }
    __syncthreads();
    if (tid < 64) {                       // softmax over 128 logits
        float beta = scal[1];
        float l0 = beta * cosb[tid], l1 = beta * cosb[tid + 64];
        float mx = fmaxf(l0, l1);
        #pragma unroll
        for (int o = 32; o >= 1; o >>= 1) mx = fmaxf(mx, __shfl_xor(mx, o));
        float e0 = expf(l0 - mx), e1 = expf(l1 - mx);
        float s = e0 + e1;
        #pragma unroll
        for (int o = 32; o >= 1; o >>= 1) s += __shfl_xor(s, o);
        float inv = 1.0f / s;
        wb[tid] = e0 * inv;
        wb[tid + 64] = e1 * inv;
    }
    __syncthreads();
    {   // FUSED read+update: thread (j, rh) walks rows rh*64..rh*64+63 of col j.
        // p += w_r * M_old[r][j];  M[r][j] = M_old - w_r*(e_j*M_old - a_j)
        int j = tid & 127, rh = tid >> 7;
        float ej = ev[j], aj = av[j];
        const float4* wb4 = (const float4*)(wb + rh * 64);
        float p = 0.f;
        #pragma unroll
        for (int q = 0; q < 16; ++q) {
            float4 w4 = wb4[q];
            int r = rh * 64 + 4 * q;
            float m0 = M[r][j], m1 = M[r + 1][j], m2 = M[r + 2][j], m3 = M[r + 3][j];
            p = fmaf(w4.x, m0, p);
            p = fmaf(w4.y, m1, p);
            p = fmaf(w4.z, m2, p);
            p = fmaf(w4.w, m3, p);
            M[r][j]     = fmaf(-w4.x, fmaf(ej, m0, -aj), m0);
            M[r + 1][j] = fmaf(-w4.y, fmaf(ej, m1, -aj), m1);
            M[r + 2][j] = fmaf(-w4.z, fmaf(ej, m2, -aj), m2);
            M[r + 3][j] = fmaf(-w4.w, fmaf(ej, m3, -aj), m3);
        }
        part[rh * 128 + j] = p;
    }
    __syncthreads();
    if (tid < 128) readv[tid] = part[tid] + part[128 + tid];
    // no barrier needed: readv[tid] is produced and consumed by thread tid,
    // and all other LDS reuse is separated by next-iteration barriers.
}

// Round-4 shape EXACTLY (256-thr WG, 1 row, ~73 KB LDS, 2 WG/CU, 512 WGs).
// vs round 8: fp16 acts + v_dot2 (half the GEMV VALU), fused rz+inn+hn
// k-sweep (1/3 the GEMV LDS reads), fused memory_step.
__global__ __launch_bounds__(256) void ntm_fast(
    const float* __restrict__ data, const int* __restrict__ batch_sizes,
    const int* __restrict__ unsort, const float* __restrict__ M0,
    const _Float16* __restrict__ wsH, const float* __restrict__ wsB,
    float* __restrict__ out)
{
    __shared__ float M[NMEM][NWORD + 1];
    __shared__ __align__(16) _Float16 actH[NACT];   // fp16 GEMV inputs
    __shared__ __align__(16) float ctrlB[NCTRL];    // fp32 ctrl master
    __shared__ __align__(16) float readv[NWORD], keyv[NWORD], ev[NWORD], av[NWORD];
    __shared__ __align__(16) float cosb[NMEM], wb[NMEM], part[2 * NWORD], scal[2];
    __shared__ int len_sh;

    const int tid = threadIdx.x;
    const int g = blockIdx.x;
    const int b = unsort[g];

    if (tid == 0) {
        int L = 0;
        for (int t = 0; t < NT; ++t) L += (batch_sizes[t] > b);
        len_sh = L;
    }
    for (int i = tid; i < NMEM * NWORD; i += 256)
        M[i >> 7][i & 127] = M0[i];
    ctrlB[tid] = 0.0f;
    if (tid < NWORD) readv[tid] = 0.0f;
    __syncthreads();
    const int len = len_sh;

    const float bA0 = wsB[B_BA + tid],  bA1 = wsB[B_BA + 256 + tid];
    const float bNi = wsB[B_BNI + tid], bNh = wsB[B_BNH + tid];
    const float bH0 = wsB[B_BH + tid],  bH1 = wsB[B_BH + 256 + tid];

    const h8* __restrict__ pA  = (const h8*)(wsH + H_WA);
    const h8* __restrict__ pI  = (const h8*)(wsH + H_WNI);
    const h8* __restrict__ pH  = (const h8*)(wsH + H_WNH);
    const h8* __restrict__ pHD = (const h8*)(wsH + H_WH);
    const h8* A8 = (const h8*)actH;

    for (int t = 0; t < len; ++t) {
        // ---- stage activations as fp16 (state masters stay fp32)
        if (tid < 64)  actH[tid] = (_Float16)data[((long)t * NB + b) * NDIN + tid];
        if (tid < 128) actH[64 + tid] = (_Float16)readv[tid];
        actH[192 + tid] = (_Float16)ctrlB[tid];
        __syncthreads();

        // ---- fused sweep: rz (cols tid, tid+256) + inn/hn (col tid)
        float a0 = bA0, a1 = bA1, c0 = 0.f, c1 = 0.f;
        float ai = bNi, ci = 0.f, ah = bNh, ch = 0.f;
        #pragma unroll 4
        for (int kc = 0; kc < 24; ++kc) {            // k in [0,192): rz + inn
            H8 x;  x.v  = A8[kc];
            H8 w0; w0.v = pA[kc * 512 + tid];
            H8 w1; w1.v = pA[kc * 512 + tid + 256];
            H8 wn; wn.v = pI[kc * 256 + tid];
            a0 = fdot2(x.d[0], w0.d[0], a0); c0 = fdot2(x.d[1], w0.d[1], c0);
            a0 = fdot2(x.d[2], w0.d[2], a0); c0 = fdot2(x.d[3], w0.d[3], c0);
            a1 = fdot2(x.d[0], w1.d[0], a1); c1 = fdot2(x.d[1], w1.d[1], c1);
            a1 = fdot2(x.d[2], w1.d[2], a1); c1 = fdot2(x.d[3], w1.d[3], c1);
            ai = fdot2(x.d[0], wn.d[0], ai); ci = fdot2(x.d[1], wn.d[1], ci);
            ai = fdot2(x.d[2], wn.d[2], ai); ci = fdot2(x.d[3], wn.d[3], ci);
        }
        #pragma unroll 4
        for (int kc = 24; kc < 56; ++kc) {           // k in [192,448): rz + hn
            H8 x;  x.v  = A8[kc];
            H8 w0; w0.v = pA[kc * 512 + tid];
            H8 w1; w1.v = pA[kc * 512 + tid + 256];
            H8 wn; wn.v = pH[(kc - 24) * 256 + tid];
            a0 = fdot2(x.d[0], w0.d[0], a0); c0 = fdot2(x.d[1], w0.d[1], c0);
            a0 = fdot2(x.d[2], w0.d[2], a0); c0 = fdot2(x.d[3], w0.d[3], c0);
            a1 = fdot2(x.d[0], w1.d[0], a1); c1 = fdot2(x.d[1], w1.d[1], c1);
            a1 = fdot2(x.d[2], w1.d[2], a1); c1 = fdot2(x.d[3], w1.d[3], c1);
            ah = fdot2(x.d[0], wn.d[0], ah); ch = fdot2(x.d[1], wn.d[1], ch);
            ah = fdot2(x.d[2], wn.d[2], ah); ch = fdot2(x.d[3], wn.d[3], ch);
        }
        a0 += c0; a1 += c1; ai += ci; ah += ch;

        float rg = sigf(a0), zg = sigf(a1);
        float ng = tanhf(fmaf(rg, ah, ai));
        float cold = ctrlB[tid];            // fp32 master (own element)
        float cnew = fmaf(zg, cold - ng, ng);
        __syncthreads();                    // all GEMV reads of actH done
        ctrlB[tid] = cnew;
        actH[192 + tid] = (_Float16)cnew;
        __syncthreads();

        // ---- heads: cols (tid, tid+256), 32 chunks over new ctrl
        float h0 = bH0, h1 = bH1, d0 = 0.f, d1 = 0.f;
        #pragma unroll 4
        for (int kc = 0; kc < 32; ++kc) {
            H8 x;  x.v  = A8[24 + kc];
            H8 w0; w0.v = pHD[kc * 512 + tid];
            H8 w1; w1.v = pHD[kc * 512 + tid + 256];
            h0 = fdot2(x.d[0], w0.d[0], h0); d0 = fdot2(x.d[1], w0.d[1], d0);
            h0 = fdot2(x.d[2], w0.d[2], h0); d0 = fdot2(x.d[3], w0.d[3], d0);
            h1 = fdot2(x.d[0], w1.d[0], h1); d1 = fdot2(x.d[1], w1.d[1], d1);
            h1 = fdot2(x.d[2], w1.d[2], h1); d1 = fdot2(x.d[3], w1.d[3], d1);
        }
        h0 += d0; h1 += d1;

        if (tid < 128) { keyv[tid] = tanhf(h0); av[tid] = h1; }
        else           { ev[tid - 128] = sigf(h0); }
        if (tid == 128) scal[1] = softplusf(h1);   // col 384 = beta
        __syncthreads();

        memory_step(tid, M, keyv, ev, av, cosb, wb, part, readv, scal);
    }

    out[g * NCTRL + tid] = ctrlB[tid];
    if (tid < NWORD) out[NB * NCTRL + g * NWORD + tid] = readv[tid];
}

// FALLBACK (ws too small): round-4 verified slow path (own memory code).
__global__ __launch_bounds__(256) void ntm_slow(
    const float* __restrict__ data, const int* __restrict__ batch_sizes,
    const int* __restrict__ unsort,
    const float* __restrict__ Wih, const float* __restrict__ bih,
    const float* __restrict__ Whh, const float* __restrict__ bhh,
    const float* __restrict__ Wkey, const float* __restrict__ bkey,
    const float* __restrict__ Wbeta, const float* __restrict__ bbeta,
    const float* __restrict__ Wer, const float* __restrict__ ber,
    const float* __restrict__ Wadd, const float* __restrict__ badd,
    const float* __restrict__ M0, float* __restrict__ out)
{
    __shared__ float M[NMEM][NWORD + 1];
    __shared__ float act[NACT];
    __shared__ float ctrlB[NCTRL];
    __shared__ float gpre[512], ginn[256], ghn[256], hpre[448];
    __shared__ __align__(16) float readv[NWORD], keyv[NWORD], ev[NWORD], av[NWORD];
    __shared__ __align__(16) float cosb[NMEM], wb[NMEM], part[2 * NWORD], scal[2];
    __shared__ int len_sh;

    const int tid = threadIdx.x;
    const int g = blockIdx.x;
    const int b = unsort[g];

    if (tid == 0) {
        int L = 0;
        for (int t = 0; t < NT; ++t) L += (batch_sizes[t] > b);
        len_sh = L;
    }
    for (int i = tid; i < NMEM * NWORD; i += 256)
        M[i >> 7][i & 127] = M0[i];
    ctrlB[tid] = 0.0f;
    if (tid < NWORD) readv[tid] = 0.0f;
    __syncthreads();
    const int len = len_sh;
    const int wave = tid >> 6, lane = tid & 63;

    for (int t = 0; t < len; ++t) {
        if (tid < 64)  act[tid] = data[((long)t * NB + b) * NDIN + tid];
        if (tid < 128) act[64 + tid] = readv[tid];
        act[192 + tid] = ctrlB[tid];
        __syncthreads();

        for (int j = wave; j < 512; j += 4) {
            float p = 0.f;
            for (int k = lane; k < 192; k += 64) p = fmaf(act[k], Wih[j * 192 + k], p);
            for (int k = lane; k < 256; k += 64) p = fmaf(act[192 + k], Whh[j * 256 + k], p);
            #pragma unroll
            for (int o = 32; o >= 1; o >>= 1) p += __shfl_xor(p, o);
            if (lane == 0) gpre[j] = p;
        }
        for (int j = wave; j < 256; j += 4) {
            float pi = 0.f, ph = 0.f;
            for (int k = lane; k < 192; k += 64) pi = fmaf(act[k], Wih[(512 + j) * 192 + k], pi);
            for (int k = lane; k < 256; k += 64) ph = fmaf(act[192 + k], Whh[(512 + j) * 256 + k], ph);
            #pragma unroll
            for (int o = 32; o >= 1; o >>= 1) { pi += __shfl_xor(pi, o); ph += __shfl_xor(ph, o); }
            if (lane == 0) { ginn[j] = pi; ghn[j] = ph; }
        }
        __syncthreads();
        {
            float r = sigf(gpre[tid] + bih[tid] + bhh[tid]);
            float z = sigf(gpre[256 + tid] + bih[256 + tid] + bhh[256 + tid]);
            float inn = ginn[tid] + bih[512 + tid];
            float hn  = ghn[tid] + bhh[512 + tid];
            float n = tanhf(fmaf(r, hn, inn));
            float cold = act[192 + tid];
            ctrlB[tid] = fmaf(z, cold - n, n);
        }
        __syncthreads();
        for (int j = wave; j < 385; j += 4) {
            const float* Wp; long base;
            if (j < 128)      { Wp = Wkey;  base = (long)j * 256; }
            else if (j < 256) { Wp = Wer;   base = (long)(j - 128) * 256; }
            else if (j < 384) { Wp = Wadd;  base = (long)(j - 256) * 256; }
            else              { Wp = Wbeta; base = 0; }
            float p = 0.f;
            for (int k = lane; k < 256; k += 64) p = fmaf(ctrlB[k], Wp[base + k], p);
            #pragma unroll
            for (int o = 32; o >= 1; o >>= 1) p += __shfl_xor(p, o);
            if (lane == 0) hpre[j] = p;
        }
        __syncthreads();
        if (tid < 128) {
            keyv[tid] = tanhf(hpre[tid] + bkey[tid]);
            ev[tid]   = sigf(hpre[128 + tid] + ber[tid]);
            av[tid]   = hpre[256 + tid] + badd[tid];
        }
        if (tid == 0) scal[1] = softplusf(hpre[384] + bbeta[0]);
        __syncthreads();

        memory_step(tid, M, keyv, ev, av, cosb, wb, part, readv, scal);
        __syncthreads();
    }

    out[g * NCTRL + tid] = ctrlB[tid];
    if (tid < NWORD) out[NB * NCTRL + g * NWORD + tid] = readv[tid];
}

extern "C" void kernel_launch(void* const* d_in, const int* in_sizes, int n_in,
                              void* d_out, int out_size, void* d_ws, size_t ws_size,
                              hipStream_t stream)
{
    const float* data       = (const float*)d_in[0];
    const int*  batch_sizes = (const int*)d_in[1];
    const int*  unsort      = (const int*)d_in[2];
    float* out = (float*)d_out;

    if (ws_size >= (size_t)WS_BYTES) {
        _Float16* wsH = (_Float16*)d_ws;
        float* wsB = (float*)((char*)d_ws + (size_t)H_TOTAL * 2);
        prep_kernel<<<(H_TOTAL + B_TOTAL + 255) / 256, 256, 0, stream>>>(
            (const float*)d_in[3], (const float*)d_in[4], (const float*)d_in[5],
            (const float*)d_in[6], (const float*)d_in[7], (const float*)d_in[8],
            (const float*)d_in[9], (const float*)d_in[10], (const float*)d_in[11],
            (const float*)d_in[12], (const float*)d_in[13], (const float*)d_in[14],
            wsH, wsB);
        ntm_fast<<<NB, 256, 0, stream>>>(data, batch_sizes, unsort,
                                         (const float*)d_in[15], wsH, wsB, out);
    } else {
        ntm_slow<<<NB, 256, 0, stream>>>(
            data, batch_sizes, unsort,
            (const float*)d_in[3], (const float*)d_in[4], (const float*)d_in[5],
            (const float*)d_in[6], (const float*)d_in[7], (const float*)d_in[8],
            (const float*)d_in[9], (const float*)d_in[10], (const float*)d_in[11],
            (const float*)d_in[12], (const float*)d_in[13], (const float*)d_in[14],
            (const float*)d_in[15], out);
    }
}